// Round 6
// baseline (418.022 us; speedup 1.0000x reference)
//
#include <hip/hip_runtime.h>
#include <cstddef>
#include <type_traits>

// MediumLSTM v9: v8 minus the x-LDS pipeline, plus split MFMA accumulator chains.
// v8 post-mortem: ~4000 cyc/step stall floor; VALU issue is down to ~900/SIMD/step
// so the wall is the barrier-coupled serial chain (ds_read -> 5-deep MFMA chain ->
// shfl -> cell -> ds_write -> lgkm drain -> barrier). v9 attacks the chain:
//  (a) x goes global->register double-buffer (8x global_load_dwordx4 per wave per
//      step, issued one step ahead; all 4 waves read the same 8KB tile -> L1/L2
//      absorb the overlap, HBM unchanged). Removes staging ds_write + 4 swizzled
//      ds_reads + cvt-for-store from the lgkm queue; the pre-barrier lgkmcnt(0)
//      drain now covers only the h-writes. LDS 12.8KB -> 4.6KB.
//  (b) MFMA accumulator chains split: L1 = three independent chains (kc01, kc23,
//      h) + 2 vector adds; L2 = two independent MFMAs + add. Dependent-MFMA
//      latency on the critical path ~2.5x shorter; h-MFMA overlaps x-MFMAs.
// Everything else = v8 (512 blocks x 4 waves, tau-pair per wave, fused-rcp cell,
// lgkm-only barrier).
//
// Work map per step (wid = tid>>6, 0..3):
//   L1: all waves, tau-pair wid (10 MFMA), 2 cells/lane
//   L2: waves 0,1, unit-group wid, 2 cells/lane
//   L3: waves 2,3, row-pair wid-2, 1 cell/lane
// Parity map (P = t&1):
//   L1: reads h1s[1-P], x_t (regs);  writes h1s[P]    (h1[t])
//   L2: reads h1s[1-P], h2s[P];      writes h2s[1-P]  (h2[t-1])
//   L3: reads h2s[P], h3s[1-P];      writes h3s[P]    (h3[t-2])
//   FC: h3[63] lands in h3s[1] (iter 65).

typedef _Float16 h8_t  __attribute__((ext_vector_type(8)));
typedef __fp16   p2_t  __attribute__((ext_vector_type(2)));
typedef float    f4_t  __attribute__((ext_vector_type(4)));

#define T_LEN 64
#define D_IN  128

__device__ __forceinline__ float rcp_(float x) { return __builtin_amdgcn_rcpf(x); }

// Full LSTM cell epilogue with shared reciprocals.
//   i*g = (e2g-1) * rcp((1+e^-vi)(e2g+1));  f = rcp(1+e^-vf)
//   h   = o*tanh(c) = (e2c-1) * rcp((1+e^-vo)(e2c+1)), 2c clamped to +-30
__device__ __forceinline__ float cell_(float vi, float vf, float vg, float vo,
                                       float& c) {
    float eni = __expf(-vi);
    float enf = __expf(-vf);
    float eno = __expf(-vo);
    float e2g = __expf(2.0f * vg);
    float igg = (e2g - 1.0f) * rcp_((1.0f + eni) * (e2g + 1.0f));
    c = rcp_(1.0f + enf) * c + igg;
    float t2 = fminf(fmaxf(2.0f * c, -30.0f), 30.0f);
    float e2c = __expf(t2);
    return (e2c - 1.0f) * rcp_((1.0f + eno) * (e2c + 1.0f));
}

__device__ __forceinline__ h8_t zero8h() {
    h8_t r = { (_Float16)0.f,(_Float16)0.f,(_Float16)0.f,(_Float16)0.f,
               (_Float16)0.f,(_Float16)0.f,(_Float16)0.f,(_Float16)0.f };
    return r;
}
__device__ __forceinline__ h8_t cvt8(f4_t lo, f4_t hi) {
    union { h8_t v8; p2_t v2[4]; } u;
    u.v2[0] = __builtin_amdgcn_cvt_pkrtz(lo[0], lo[1]);
    u.v2[1] = __builtin_amdgcn_cvt_pkrtz(lo[2], lo[3]);
    u.v2[2] = __builtin_amdgcn_cvt_pkrtz(hi[0], hi[1]);
    u.v2[3] = __builtin_amdgcn_cvt_pkrtz(hi[2], hi[3]);
    return u.v8;
}
__device__ __forceinline__ h8_t load8f_h(const float* __restrict__ p) {
    f4_t lo = *(const f4_t*)p, hi = *(const f4_t*)(p + 4);
    return cvt8(lo, hi);
}

// lgkm-only barrier: LDS writes committed before the convergent barrier; global
// x loads (vmcnt) stay in flight, HW-enforced at register use.
__device__ __forceinline__ void bar_lds() {
    asm volatile("s_waitcnt lgkmcnt(0)" ::: "memory");
    __builtin_amdgcn_s_barrier();
}

__global__ __launch_bounds__(256, 2)
void lstm_one(const float* __restrict__ x,
              const float* __restrict__ w_ih1, const float* __restrict__ w_hh1,
              const float* __restrict__ b_ih1, const float* __restrict__ b_hh1,
              const float* __restrict__ w_ih2, const float* __restrict__ w_hh2,
              const float* __restrict__ b_ih2, const float* __restrict__ b_hh2,
              const float* __restrict__ w_ih3, const float* __restrict__ w_hh3,
              const float* __restrict__ b_ih3, const float* __restrict__ b_hh3,
              const float* __restrict__ fc_w, const float* __restrict__ fc_b,
              float* __restrict__ out)
{
    __shared__ __align__(16) _Float16 h1s[2][16][40];
    __shared__ __align__(16) _Float16 h2s[2][16][24];
    __shared__ __align__(16) _Float16 h3s[2][16][8];

    const int tid  = threadIdx.x;          // 0..255
    const int lane = tid & 63;
    const int wid  = tid >> 6;             // 0..3
    const int nl = lane & 15, qd = lane >> 4;
    const int n7 = nl & 7;
    const bool lo8 = (nl & 8) == 0;

    // ---------------- weights into VGPRs (per-wave slices) ----------------
    h8_t bw1[2][4], bh1[2];
    #pragma unroll
    for (int j = 0; j < 2; ++j) {
        int G = 8 * wid + n7 + 32 * ((nl >> 3) + 2 * j);
        #pragma unroll
        for (int kc = 0; kc < 4; ++kc)
            bw1[j][kc] = load8f_h(w_ih1 + G * 128 + kc * 32 + qd * 8);
        bh1[j] = load8f_h(w_hh1 + G * 32 + qd * 8);
    }
    h8_t bw2[2] = {zero8h(), zero8h()}, bh2[2] = {zero8h(), zero8h()};
    float bs2[4] = {0.f, 0.f, 0.f, 0.f};
    if (wid < 2) {
        #pragma unroll
        for (int j = 0; j < 2; ++j) {
            int G = 32 * j + 16 * (nl >> 3) + 8 * wid + n7;
            bw2[j] = load8f_h(w_ih2 + G * 32 + qd * 8);
            bh2[j] = (qd < 2) ? load8f_h(w_hh2 + G * 16 + qd * 8) : zero8h();
        }
        int u2 = 8 * wid + n7;
        #pragma unroll
        for (int g = 0; g < 4; ++g) bs2[g] = b_ih2[16 * g + u2] + b_hh2[16 * g + u2];
    }
    h8_t b3c[2] = {zero8h(), zero8h()};
    float bs3[4] = {0.f, 0.f, 0.f, 0.f};
    if (wid >= 2) {
        #pragma unroll
        for (int j = 0; j < 2; ++j) {
            int G = 16 * j + 8 * (nl >> 3) + n7;
            b3c[j] = (qd < 2) ? load8f_h(w_ih3 + G * 16 + qd * 8)
                   : (qd == 2) ? load8f_h(w_hh3 + G * 8) : zero8h();
        }
        #pragma unroll
        for (int g = 0; g < 4; ++g) bs3[g] = b_ih3[8 * g + n7] + b_hh3[8 * g + n7];
    }
    float bs1[4];
    {
        int u1 = 8 * wid + n7;
        #pragma unroll
        for (int g = 0; g < 4; ++g) bs1[g] = b_ih1[32 * g + u1] + b_hh1[32 * g + u1];
    }

    // zero both parities of all h-state LDS
    for (int i = tid; i < 2 * 16 * 40; i += 256) (&h1s[0][0][0])[i] = (_Float16)0.f;
    for (int i = tid; i < 2 * 16 * 24; i += 256) (&h2s[0][0][0])[i] = (_Float16)0.f;
    for (int i = tid; i < 2 * 16 * 8;  i += 256) (&h3s[0][0][0])[i] = (_Float16)0.f;

    float c1[2] = {0.f, 0.f};   // L1 cells, rows rr (lo8) / rr+2 (hi8)
    float c2[2] = {0.f, 0.f};   // L2 cells (waves 0,1)
    float c3    = 0.f;          // L3 cell  (waves 2,3)

    const int b0 = blockIdx.x * 16;

    // ---------------- per-lane direct x fragments (register double-buffer) ------
    // Lane l consumes x[row b0+nl][t][kc*32 + qd*8 .. +7]: exactly the MFMA A-frag.
    // Each wave reads the full 8KB step-tile; 4 waves overlap via L1/L2 (HBM 1x).
    // Loaded one step ahead into xr (vmcnt-tracked; never drained by bar_lds).
    const float* xgl = x + ((size_t)(b0 + nl) * T_LEN) * D_IN + qd * 8;
    f4_t xr[8];
    #pragma unroll
    for (int kc = 0; kc < 4; ++kc) {                  // x_0
        xr[2 * kc]     = *(const f4_t*)(xgl + kc * 32);
        xr[2 * kc + 1] = *(const f4_t*)(xgl + kc * 32 + 4);
    }
    bar_lds();   // h-state zero-init visible

    // ---------------- one pipelined iteration ----------------
    auto step = [&](auto d1c, auto d2c, auto d3c, auto pc, int t) {
        constexpr bool DO1 = decltype(d1c)::value;
        constexpr bool DO2 = decltype(d2c)::value;
        constexpr bool DO3 = decltype(d3c)::value;
        constexpr int  P   = decltype(pc)::value;

        h8_t a1p = zero8h();
        if constexpr (DO1 || DO2)
            a1p = *(const h8_t*)&h1s[1 - P][nl][qd * 8];             // h1[t-1]

        if constexpr (DO1) {
            // convert x_t (regs), then refill xr with x_{t+1} (clamped)
            h8_t af[4];
            #pragma unroll
            for (int kc = 0; kc < 4; ++kc) af[kc] = cvt8(xr[2 * kc], xr[2 * kc + 1]);
            {
                int tn = (t + 1 < T_LEN) ? (t + 1) : t;
                const float* xn = xgl + (size_t)tn * D_IN;
                #pragma unroll
                for (int kc = 0; kc < 4; ++kc) {
                    xr[2 * kc]     = *(const f4_t*)(xn + kc * 32);
                    xr[2 * kc + 1] = *(const f4_t*)(xn + kc * 32 + 4);
                }
            }

            f4_t acc[2];
            #pragma unroll
            for (int j = 0; j < 2; ++j) {
                // three independent chains; sum at the end
                f4_t z = {0.f, 0.f, 0.f, 0.f};
                f4_t ax = __builtin_amdgcn_mfma_f32_16x16x32_f16(af[0], bw1[j][0], z, 0, 0, 0);
                ax = __builtin_amdgcn_mfma_f32_16x16x32_f16(af[1], bw1[j][1], ax, 0, 0, 0);
                f4_t ay = __builtin_amdgcn_mfma_f32_16x16x32_f16(af[2], bw1[j][2], z, 0, 0, 0);
                ay = __builtin_amdgcn_mfma_f32_16x16x32_f16(af[3], bw1[j][3], ay, 0, 0, 0);
                f4_t ah = __builtin_amdgcn_mfma_f32_16x16x32_f16(a1p, bh1[j], z, 0, 0, 0);
                acc[j] = (ax + ay) + ah;
            }
            // acc[0]: lo=i / hi=f ; acc[1]: lo=g / hi=o. One shfl per reg pair.
            #pragma unroll
            for (int rr = 0; rr < 2; ++rr) {
                float s0 = lo8 ? acc[0][rr + 2] : acc[0][rr];
                float s1 = lo8 ? acc[1][rr + 2] : acc[1][rr];
                float x0 = __shfl_xor(s0, 8, 64);
                float x1 = __shfl_xor(s1, 8, 64);
                float vi = lo8 ? acc[0][rr] : x0;
                float vf = lo8 ? x0 : acc[0][rr + 2];
                float vg = lo8 ? acc[1][rr] : x1;
                float vo = lo8 ? x1 : acc[1][rr + 2];
                float h = cell_(vi + bs1[0], vf + bs1[1], vg + bs1[2], vo + bs1[3], c1[rr]);
                h1s[P][4 * qd + rr + (lo8 ? 0 : 2)][8 * wid + n7] = (_Float16)h;  // h1[t]
            }
        }

        if constexpr (DO2) {
            if (wid < 2) {
                h8_t a2p = zero8h();
                if (qd < 2) a2p = *(const h8_t*)&h2s[P][nl][qd * 8]; // h2[t-2]
                f4_t acc2[2];
                #pragma unroll
                for (int j = 0; j < 2; ++j) {
                    f4_t z = {0.f, 0.f, 0.f, 0.f};
                    f4_t m1 = __builtin_amdgcn_mfma_f32_16x16x32_f16(a1p, bw2[j], z, 0, 0, 0);
                    f4_t m2 = __builtin_amdgcn_mfma_f32_16x16x32_f16(a2p, bh2[j], z, 0, 0, 0);
                    acc2[j] = m1 + m2;
                }
                #pragma unroll
                for (int rr = 0; rr < 2; ++rr) {
                    float s0 = lo8 ? acc2[0][rr + 2] : acc2[0][rr];
                    float s1 = lo8 ? acc2[1][rr + 2] : acc2[1][rr];
                    float x0 = __shfl_xor(s0, 8, 64);
                    float x1 = __shfl_xor(s1, 8, 64);
                    float vi = lo8 ? acc2[0][rr] : x0;
                    float vf = lo8 ? x0 : acc2[0][rr + 2];
                    float vg = lo8 ? acc2[1][rr] : x1;
                    float vo = lo8 ? x1 : acc2[1][rr + 2];
                    float h = cell_(vi + bs2[0], vf + bs2[1], vg + bs2[2], vo + bs2[3], c2[rr]);
                    h2s[1 - P][4 * qd + rr + (lo8 ? 0 : 2)][8 * wid + n7] = (_Float16)h; // h2[t-1]
                }
            }
        }

        if constexpr (DO3) {
            if (wid >= 2) {
                h8_t a3 = zero8h();
                if (qd < 2)       a3 = *(const h8_t*)&h2s[P][nl][qd * 8];  // h2[t-2]
                else if (qd == 2) a3 = *(const h8_t*)&h3s[1 - P][nl][0];   // h3[t-3]
                f4_t acc3[2];
                #pragma unroll
                for (int j = 0; j < 2; ++j) {
                    f4_t z = {0.f, 0.f, 0.f, 0.f};
                    acc3[j] = __builtin_amdgcn_mfma_f32_16x16x32_f16(a3, b3c[j], z, 0, 0, 0);
                }
                auto l3c = [&](auto rpc) {
                    constexpr int rp = decltype(rpc)::value;
                    float eLo = acc3[0][rp],     oLo = acc3[1][rp];
                    float eHi = acc3[0][rp + 2], oHi = acc3[1][rp + 2];
                    float se = lo8 ? eHi : eLo; float xe = __shfl_xor(se, 8, 64);
                    float so = lo8 ? oHi : oLo; float xo = __shfl_xor(so, 8, 64);
                    float vi = lo8 ? eLo : xe;
                    float vf = lo8 ? xe  : eHi;
                    float vg = lo8 ? oLo : xo;
                    float vo = lo8 ? xo  : oHi;
                    float h = cell_(vi + bs3[0], vf + bs3[1], vg + bs3[2], vo + bs3[3], c3);
                    h3s[P][4 * qd + rp + (lo8 ? 0 : 2)][n7] = (_Float16)h;  // h3[t-2]
                };
                if (wid == 2) l3c(std::integral_constant<int, 0>{});
                else          l3c(std::integral_constant<int, 1>{});
            }
        }

        bar_lds();
    };

    using TT = std::integral_constant<bool, true>;
    using FF = std::integral_constant<bool, false>;
    using P0 = std::integral_constant<int, 0>;
    using P1 = std::integral_constant<int, 1>;

    // warm-up
    step(TT{}, FF{}, FF{}, P0{}, 0);
    step(TT{}, TT{}, FF{}, P1{}, 1);
    // main: t = 2..63, parity static via x2 unroll
    for (int tb = 1; tb < 32; ++tb) {
        step(TT{}, TT{}, TT{}, P0{}, 2 * tb);
        step(TT{}, TT{}, TT{}, P1{}, 2 * tb + 1);
    }
    // drain
    step(FF{}, TT{}, TT{}, P0{}, 64);
    step(FF{}, FF{}, TT{}, P1{}, 65);

    // ---------------- FC head: h3[63] is in h3s[1] ----------------
    if (tid < 16) {
        float a = fc_b[0];
        #pragma unroll
        for (int u = 0; u < 8; ++u)
            a += fc_w[u] * (float)h3s[1][tid][u];
        out[b0 + tid] = a;
    }
}

extern "C" void kernel_launch(void* const* d_in, const int* in_sizes, int n_in,
                              void* d_out, int out_size, void* d_ws, size_t ws_size,
                              hipStream_t stream) {
    (void)in_sizes; (void)n_in; (void)out_size; (void)d_ws; (void)ws_size;
    const float* x     = (const float*)d_in[0];
    const float* w_ih1 = (const float*)d_in[1];
    const float* w_hh1 = (const float*)d_in[2];
    const float* b_ih1 = (const float*)d_in[3];
    const float* b_hh1 = (const float*)d_in[4];
    const float* w_ih2 = (const float*)d_in[5];
    const float* w_hh2 = (const float*)d_in[6];
    const float* b_ih2 = (const float*)d_in[7];
    const float* b_hh2 = (const float*)d_in[8];
    const float* w_ih3 = (const float*)d_in[9];
    const float* w_hh3 = (const float*)d_in[10];
    const float* b_ih3 = (const float*)d_in[11];
    const float* b_hh3 = (const float*)d_in[12];
    const float* fc_w  = (const float*)d_in[13];
    const float* fc_b  = (const float*)d_in[14];

    dim3 grid(512), block(256);
    hipLaunchKernelGGL(lstm_one, grid, block, 0, stream,
                       x, w_ih1, w_hh1, b_ih1, b_hh1,
                       w_ih2, w_hh2, b_ih2, b_hh2,
                       w_ih3, w_hh3, b_ih3, b_hh3,
                       fc_w, fc_b, (float*)d_out);
}